// Round 3
// baseline (154.933 us; speedup 1.0000x reference)
//
#include <hip/hip_runtime.h>

#define N_CLS 100
#define D_DIM 256
#define MAX_M 112            // fast-path row capacity (7 tiles of 16)
#define ROW_SH 264           // shorts per LDS row = 528 B: 16B-aligned, 2-way banks (free)
#define PANEL 48             // slow-path panel rows — only if some class m > 112
#define PACK_CAP 128         // packed rows per class (>= MAX_M; fast path only)
#define CNT_STR 32           // int stride between class counters = 128 B (atomic line sep)
#define POISON 0xAAAAAAAAu   // harness ws poison pattern (re-poisoned every launch)
#define GRID_B 512           // 2 blocks/CU at 59.9KB LDS -> all co-resident
#define TW (GRID_B * 8)      // total prep waves = 4096

typedef short bf16x8 __attribute__((ext_vector_type(8)));
typedef float f32x4  __attribute__((ext_vector_type(4)));

__device__ __forceinline__ unsigned short f2bf(float f) {   // fp32 -> bf16 RNE
    unsigned int b = __float_as_uint(f);
    return (unsigned short)((b + 0x7FFFu + ((b >> 16) & 1u)) >> 16);
}

// Pack one row (wave-per-row, lane = float4 chunk) into class-packed bf16 + exact sq.
__device__ __forceinline__ void emit_row(float4 v, int c, int pos, int lane,
        float* __restrict__ sqp, unsigned short* __restrict__ packed) {
    float s = v.x * v.x + v.y * v.y + v.z * v.z + v.w * v.w;   // exact fp32 ||row||^2
    #pragma unroll
    for (int o = 32; o; o >>= 1) s += __shfl_xor(s, o, 64);
    if (pos < PACK_CAP) {                                      // wave-uniform
        short4 pk;
        pk.x = (short)f2bf(v.x); pk.y = (short)f2bf(v.y);
        pk.z = (short)f2bf(v.z); pk.w = (short)f2bf(v.w);
        *(short4*)(packed + ((size_t)c * PACK_CAP + pos) * D_DIM + lane * 4) = pk;
        if (lane == 0) sqp[c * PACK_CAP + pos] = s;
    }
}

// FALLBACK ONLY (m > MAX_M): stage rows from pred via bucket list into LDS.
__device__ __forceinline__ void stage(const float* __restrict__ pred,
        const int* bkt, int m, int cp0, int dslot, int cnt,
        short* tileS, float* sqs, int wave, int lane) {
    for (int r = wave; r < cnt; r += 8) {
        int cp = cp0 + r;
        float4 v = make_float4(0.f, 0.f, 0.f, 0.f);
        if (cp < m) {
            int g = bkt[cp];
            v = ((const float4*)(pred + (size_t)g * D_DIM))[lane];
        }
        short4 pk;
        pk.x = (short)f2bf(v.x); pk.y = (short)f2bf(v.y);
        pk.z = (short)f2bf(v.z); pk.w = (short)f2bf(v.w);
        *(short4*)&tileS[(dslot + r) * ROW_SH + lane * 4] = pk;
        float s = v.x * v.x + v.y * v.y + v.z * v.z + v.w * v.w;
        #pragma unroll
        for (int o = 32; o; o >>= 1) s += __shfl_xor(s, o, 64);
        if (lane == 0) sqs[dslot + r] = s;
    }
}

// One 16x16 MFMA tile. C/D layout (HW-verified): col=lane&15 -> B row,
// row=(lane>>4)*4+rr -> A row. d2 = sq_i + sq_j - 2*G_ij (sq exact fp32).
__device__ __forceinline__ float tile16(const short* tileS, const float* sqs,
        int a0, int b0, int ga0, int gb0, int m, int lane) {
    const int q = lane >> 4, l15 = lane & 15;
    const short* aP = &tileS[(a0 + l15) * ROW_SH + q * 8];
    const short* bP = &tileS[(b0 + l15) * ROW_SH + q * 8];
    f32x4 acc = {0.f, 0.f, 0.f, 0.f};
    #pragma unroll
    for (int ks = 0; ks < 8; ++ks) {
        bf16x8 af = *(const bf16x8*)(aP + ks * 32);
        bf16x8 bg = *(const bf16x8*)(bP + ks * 32);
        acc = __builtin_amdgcn_mfma_f32_16x16x32_bf16(af, bg, acc, 0, 0, 0);
    }
    float out = 0.f;
    #pragma unroll
    for (int rr = 0; rr < 4; ++rr) {
        int al = q * 4 + rr;
        int pi = ga0 + al, pj = gb0 + l15;
        float d2 = sqs[a0 + al] + sqs[b0 + l15] - 2.f * acc[rr];
        if (pj < m && pi < pj) out += sqrtf(fmaxf(d2, 0.f));
    }
    return out;
}

// ---------------- Fused kernel: all blocks prep, first N_CLS gram + finalize -------------
// Protocols (all poison-based; ws re-poisoned 0xAA every launch):
//   cnt[c]:    starts POISON; pos = atomicAdd - POISON. Self-restored by class block.
//   rows_done: starts POISON; each block release-adds its prep row count; gram blocks
//              spin until == POISON + n, then acquire-fence. Restored by block 0.
//   pcnt[c]:   poison is negative; publish makes it >= 0. Restored by block 0 post-read.
// Deadlock safety: spinners only spin AFTER contributing; spinners are <=100 blocks so
// contributors always have free CUs; non-spinner blocks retire unconditionally.
__global__ __launch_bounds__(512) void k_fused(const float* __restrict__ pred,
        const int* __restrict__ targets, int n, int* __restrict__ cnt,
        int* __restrict__ bucket_g, float* __restrict__ sqp,
        unsigned short* __restrict__ packed, int* __restrict__ rows_done,
        double* __restrict__ psum, double* __restrict__ pcnt, float* __restrict__ out) {
    __shared__ short tileS[MAX_M * ROW_SH];   // 59136 B
    __shared__ float sqs[MAX_M];
    __shared__ float wsum[8];
    const int t = threadIdx.x, lane = t & 63, wave = t >> 6;
    const int gw = (int)(blockIdx.x * 8 + wave);

    // ---- prep: 2 rows per wave, both loads in flight before processing ----
    {
        const int r0 = gw, r1 = gw + TW;
        const bool h0 = r0 < n, h1 = r1 < n;
        float4 v0 = make_float4(0,0,0,0), v1 = make_float4(0,0,0,0);
        int c0 = 0, c1 = 0;
        if (h0) { c0 = targets[r0]; v0 = ((const float4*)(pred + (size_t)r0 * D_DIM))[lane]; }
        if (h1) { c1 = targets[r1]; v1 = ((const float4*)(pred + (size_t)r1 * D_DIM))[lane]; }
        int p0 = 0, p1 = 0;
        if (lane == 0) {
            if (h0) { p0 = (int)((unsigned)atomicAdd(&cnt[c0 * CNT_STR], 1) - POISON);
                      bucket_g[(size_t)c0 * n + p0] = r0; }
            if (h1) { p1 = (int)((unsigned)atomicAdd(&cnt[c1 * CNT_STR], 1) - POISON);
                      bucket_g[(size_t)c1 * n + p1] = r1; }
        }
        p0 = __shfl(p0, 0, 64); p1 = __shfl(p1, 0, 64);
        if (h0) emit_row(v0, c0, p0, lane, sqp, packed);
        if (h1) emit_row(v1, c1, p1, lane, sqp, packed);
        for (int r = gw + 2 * TW; r < n; r += TW) {          // generic residual (n>2*TW)
            int c = targets[r];
            float4 v = ((const float4*)(pred + (size_t)r * D_DIM))[lane];
            int p = 0;
            if (lane == 0) { p = (int)((unsigned)atomicAdd(&cnt[c * CNT_STR], 1) - POISON);
                             bucket_g[(size_t)c * n + p] = r; }
            p = __shfl(p, 0, 64);
            emit_row(v, c, p, lane, sqp, packed);
        }
    }
    // ---- signal: one release-ordered atomic per block ----
    __threadfence();                          // device-scope release of packed/sqp/bucket
    __syncthreads();
    if (t == 0) {
        int blkRows = 0;
        #pragma unroll
        for (int w = 0; w < 8; ++w) {
            int g = (int)(blockIdx.x * 8 + w);
            if (g < n) blkRows += (n - 1 - g) / TW + 1;
        }
        __hip_atomic_fetch_add(rows_done, blkRows, __ATOMIC_RELEASE, __HIP_MEMORY_SCOPE_AGENT);
    }
    if (blockIdx.x >= N_CLS) return;          // prep-only blocks retire (never spin)

    // ---- wait for all rows bucketed+packed ----
    if (t == 0) {
        const unsigned tgt = POISON + (unsigned)n;
        while (__hip_atomic_load((const unsigned*)rows_done, __ATOMIC_ACQUIRE,
                                 __HIP_MEMORY_SCOPE_AGENT) != tgt)
            __builtin_amdgcn_s_sleep(1);
    }
    __syncthreads();
    __threadfence();                          // device-scope acquire before reading packed

    const int c = blockIdx.x;
    const int m = (int)((unsigned)cnt[c * CNT_STR] - POISON);
    float accum = 0.f;

    if (m <= MAX_M) {
        const int T = (m + 15) >> 4;          // 0 if m==0
        // Flat coalesced copy: m contiguous 512B bf16 rows (L3-warm) into padded LDS.
        // Rows m..T*16-1 left as garbage: consumers masked by (pj<m && pi<pj).
        const int4* srcv = (const int4*)(packed + (size_t)c * PACK_CAP * D_DIM);
        for (int k = t; k < m * 32; k += 512)            // 16B chunks, row = k>>5
            *(int4*)&tileS[(k >> 5) * ROW_SH + (k & 31) * 8] = srcv[k];
        if (t < m) sqs[t] = sqp[c * PACK_CAP + t];
        __syncthreads();
        const int np = T * (T + 1) / 2;
        for (int idx = wave; idx < np; idx += 8) {
            int ta = 0, r = idx;
            while (r >= T - ta) { r -= T - ta; ++ta; }
            int tb = ta + r;
            accum += tile16(tileS, sqs, ta * 16, tb * 16, ta * 16, tb * 16, m, lane);
        }
    } else {
        // general fallback: 48-row panel pairs (correct for any m; ~never runs)
        const int* bkt_g = bucket_g + (size_t)c * n;
        const int P = (m + PANEL - 1) / PANEL;
        for (int pi = 0; pi < P; ++pi)
        for (int pj = pi; pj < P; ++pj) {
            __syncthreads();
            stage(pred, bkt_g, m, pi * PANEL, 0,     PANEL, tileS, sqs, wave, lane);
            stage(pred, bkt_g, m, pj * PANEL, PANEL, PANEL, tileS, sqs, wave, lane);
            __syncthreads();
            for (int idx = wave; idx < 9; idx += 8) {
                int ta = idx / 3, tb = idx % 3;
                accum += tile16(tileS, sqs, ta * 16, PANEL + tb * 16,
                                pi * PANEL + ta * 16, pj * PANEL + tb * 16, m, lane);
            }
        }
    }

    #pragma unroll
    for (int o = 32; o; o >>= 1) accum += __shfl_xor(accum, o, 64);
    if (lane == 0) wsum[wave] = accum;
    __syncthreads();
    if (t == 0) {
        double bs = 0.0;
        #pragma unroll
        for (int w = 0; w < 8; ++w) bs += (double)wsum[w];
        __hip_atomic_store(&psum[c], bs, __ATOMIC_RELAXED, __HIP_MEMORY_SCOPE_AGENT);
        __hip_atomic_store(&pcnt[c], (double)m * (double)(m - 1) * 0.5,
                           __ATOMIC_RELEASE, __HIP_MEMORY_SCOPE_AGENT);
        cnt[c * CNT_STR] = (int)POISON;   // self-restore (rocprof-replay safety)
    }

    if (c == 0) {
        // gather all 100 per-class partials (spin until each is published)
        double mys = 0.0, myc = 0.0;
        if (t < N_CLS) {
            unsigned long long bits;
            do {
                bits = __hip_atomic_load((const unsigned long long*)&pcnt[t],
                                         __ATOMIC_ACQUIRE, __HIP_MEMORY_SCOPE_AGENT);
            } while (bits >> 63);             // poison is negative; pcnt >= 0.0
            myc = __longlong_as_double((long long)bits);
            unsigned long long sb = __hip_atomic_load((const unsigned long long*)&psum[t],
                                         __ATOMIC_RELAXED, __HIP_MEMORY_SCOPE_AGENT);
            mys = __longlong_as_double((long long)sb);
            // restore "unpublished" state (safe: publisher t already passed both
            // barriers for pcnt[t] to be visible). Replay robustness only.
            __hip_atomic_store(&pcnt[t], -1.0, __ATOMIC_RELAXED, __HIP_MEMORY_SCOPE_AGENT);
        }
        __syncthreads();                      // staging data dead; reuse tileS
        double* red_s = (double*)tileS;
        double* red_c = red_s + 128;
        if (t < 128) { red_s[t] = (t < N_CLS) ? mys : 0.0;
                       red_c[t] = (t < N_CLS) ? myc : 0.0; }
        __syncthreads();
        for (int w = 64; w; w >>= 1) {
            if (t < w) { red_s[t] += red_s[t + w]; red_c[t] += red_c[t + w]; }
            __syncthreads();
        }
        if (t == 0) {
            out[0] = (float)(red_c[0] > 0.0 ? red_s[0] / red_c[0] : 0.0);
            *rows_done = (int)POISON;         // restore (all spinners provably past)
        }
    }
}

extern "C" void kernel_launch(void* const* d_in, const int* in_sizes, int n_in,
                              void* d_out, int out_size, void* d_ws, size_t ws_size,
                              hipStream_t stream) {
    const float* pred  = (const float*)d_in[0];
    const int* targets = (const int*)d_in[1];
    float* out         = (float*)d_out;
    const int n = in_sizes[1];     // 8192

    char* ws = (char*)d_ws;
    size_t off = 0;
    double* psum  = (double*)(ws + off); off += N_CLS * 8;
    double* pcnt  = (double*)(ws + off); off += N_CLS * 8;
    int* cnt      = (int*)(ws + off);    off += (size_t)N_CLS * CNT_STR * 4;
    int* rows_done= (int*)(ws + off);    off += 128;   // own cache line
    float* sqp    = (float*)(ws + off);  off += (size_t)N_CLS * PACK_CAP * 4;
    off = (off + 63) & ~(size_t)63;
    unsigned short* packed = (unsigned short*)(ws + off);
    off += (size_t)N_CLS * PACK_CAP * D_DIM * 2;          // 6.55 MB
    int* bucket_g = (int*)(ws + off);                     // N_CLS * n ints = 3.2 MB
    // total ws use ~10 MB << 256 MiB workspace

    k_fused<<<GRID_B, 512, 0, stream>>>(pred, targets, n, cnt, bucket_g, sqp, packed,
                                        rows_done, psum, pcnt, out);
}

// Round 4
// 68.859 us; speedup vs baseline: 2.2500x; 2.2500x over previous
//
#include <hip/hip_runtime.h>

#define N_CLS 100
#define D_DIM 256
#define MAX_M 112            // fast-path row capacity (7 tiles of 16)
#define ROW_SH 264           // shorts per LDS row = 528 B: 16B-aligned, 2-way banks (free)
#define PANEL 48             // slow-path panel rows — only if some class m > 112
#define HALF_R 56            // f32 async-staging rows per phase (2 phases cover MAX_M)

#define AS1 __attribute__((address_space(1)))
#define AS3 __attribute__((address_space(3)))

typedef short bf16x8 __attribute__((ext_vector_type(8)));
typedef float f32x4  __attribute__((ext_vector_type(4)));

__device__ __forceinline__ unsigned short f2bf(float f) {   // fp32 -> bf16 RNE
    unsigned int b = __float_as_uint(f);
    return (unsigned short)((b + 0x7FFFu + ((b >> 16) & 1u)) >> 16);
}

// Async global->LDS DMA, 16 B/lane. Global addr is per-lane; LDS dest is
// wave-uniform base + lane*16 (HW rule, m104/m108). Caller passes lane's gptr.
__device__ __forceinline__ void gl_lds16(const void* g, void* l) {
    __builtin_amdgcn_global_load_lds((AS1 void*)g, (AS3 void*)l, 16, 0, 0);
}

// FALLBACK ONLY (m > MAX_M): stage rows from pred via bucket list into LDS.
__device__ __forceinline__ void stage(const float* __restrict__ pred,
        const int* bkt, int m, int cp0, int dslot, int cnt,
        short* tileS, float* sqs, int wave, int lane) {
    for (int r = wave; r < cnt; r += 8) {
        int cp = cp0 + r;
        float4 v = make_float4(0.f, 0.f, 0.f, 0.f);
        if (cp < m) {
            int g = bkt[cp];
            v = ((const float4*)(pred + (size_t)g * D_DIM))[lane];
        }
        short4 pk;
        pk.x = (short)f2bf(v.x); pk.y = (short)f2bf(v.y);
        pk.z = (short)f2bf(v.z); pk.w = (short)f2bf(v.w);
        *(short4*)&tileS[(dslot + r) * ROW_SH + lane * 4] = pk;
        float s = v.x * v.x + v.y * v.y + v.z * v.z + v.w * v.w;
        #pragma unroll
        for (int o = 32; o; o >>= 1) s += __shfl_xor(s, o, 64);
        if (lane == 0) sqs[dslot + r] = s;
    }
}

// One 16x16 MFMA tile. C/D layout (HW-verified): col=lane&15 -> B row,
// row=(lane>>4)*4+rr -> A row. d2 = sq_i + sq_j - 2*G_ij (sq exact fp32).
__device__ __forceinline__ float tile16(const short* tileS, const float* sqs,
        int a0, int b0, int ga0, int gb0, int m, int lane) {
    const int q = lane >> 4, l15 = lane & 15;
    const short* aP = &tileS[(a0 + l15) * ROW_SH + q * 8];
    const short* bP = &tileS[(b0 + l15) * ROW_SH + q * 8];
    f32x4 acc = {0.f, 0.f, 0.f, 0.f};
    #pragma unroll
    for (int ks = 0; ks < 8; ++ks) {
        bf16x8 af = *(const bf16x8*)(aP + ks * 32);
        bf16x8 bg = *(const bf16x8*)(bP + ks * 32);
        acc = __builtin_amdgcn_mfma_f32_16x16x32_bf16(af, bg, acc, 0, 0, 0);
    }
    float out = 0.f;
    #pragma unroll
    for (int rr = 0; rr < 4; ++rr) {
        int al = q * 4 + rr;
        int pi = ga0 + al, pj = gb0 + l15;
        float d2 = sqs[a0 + al] + sqs[b0 + l15] - 2.f * acc[rr];
        if (pj < m && pi < pj) out += sqrtf(fmaxf(d2, 0.f));
    }
    return out;
}

// ---------- Single kernel: block-per-class (reg-scan + async-DMA stage) ----------
// No cross-block handshake except the proven write-once pcnt publish/spin tail.
// LDS: tileS 59136 + fbuf 57344 + ~1 KB = ~117 KB -> 1 block/CU (100 blocks, fine).
__global__ __launch_bounds__(512) void k_cls(const float* __restrict__ pred,
        const int* __restrict__ targets, int n, int* __restrict__ bucket_g,
        double* __restrict__ psum, double* __restrict__ pcnt, float* __restrict__ out) {
    __shared__ short tileS[MAX_M * ROW_SH];            // 59136 B
    __shared__ __align__(16) float fbuf[HALF_R * D_DIM]; // 57344 B f32 DMA landing zone
    __shared__ float sqs[MAX_M];
    __shared__ float wsum[8];
    __shared__ int bkt_s[MAX_M];
    __shared__ int cnt_s;
    const int t = threadIdx.x, lane = t & 63, wave = t >> 6;
    const int c = blockIdx.x;
    int* bkt_g = bucket_g + (size_t)c * n;    // fallback-only index list

    if (t == 0) cnt_s = 0;
    __syncthreads();

    // ---- scan targets: all loads in flight first, then process from registers ----
    if (n == 8192) {
        const int4* tg = (const int4*)targets;
        int4 tv0 = tg[0 * 512 + t], tv1 = tg[1 * 512 + t],
             tv2 = tg[2 * 512 + t], tv3 = tg[3 * 512 + t];
        const int4 tvs[4] = {tv0, tv1, tv2, tv3};
        #pragma unroll
        for (int u = 0; u < 4; ++u) {
            const int base = 4 * (u * 512 + t);
            const int vals[4] = {tvs[u].x, tvs[u].y, tvs[u].z, tvs[u].w};
            #pragma unroll
            for (int e = 0; e < 4; ++e)
                if (vals[e] == c) {
                    int pos = atomicAdd(&cnt_s, 1);   // order within class irrelevant
                    if (pos < MAX_M) bkt_s[pos] = base + e;
                    bkt_g[pos] = base + e;
                }
        }
    } else {                                          // defensive generic path
        for (int i = t; i < n; i += 512)
            if (targets[i] == c) {
                int pos = atomicAdd(&cnt_s, 1);
                if (pos < MAX_M) bkt_s[pos] = i;
                bkt_g[pos] = i;
            }
    }
    __syncthreads();
    const int m = cnt_s;
    float accum = 0.f;

    if (m <= MAX_M) {
        const int T = (m + 15) >> 4;          // 0 if m==0
        // Two async phases: wave fires all its rows' 1KB DMAs (7 in flight ->
        // one exposed HBM latency), waits vmcnt(0), converts own slots to bf16
        // + exact fp32 sq (bit-identical math/order to the proven stage()).
        #pragma unroll
        for (int ph = 0; ph < 2; ++ph) {
            const int r0 = ph * HALF_R;
            const int rend = (m < r0 + HALF_R) ? m : (r0 + HALF_R);
            for (int r = r0 + wave; r < rend; r += 8)
                gl_lds16(pred + (size_t)bkt_s[r] * D_DIM + lane * 4,
                         &fbuf[(r - r0) * D_DIM]);
            asm volatile("s_waitcnt vmcnt(0)" ::: "memory");
            for (int r = r0 + wave; r < rend; r += 8) {
                float4 v = *(const float4*)&fbuf[(r - r0) * D_DIM + lane * 4];
                short4 pk;
                pk.x = (short)f2bf(v.x); pk.y = (short)f2bf(v.y);
                pk.z = (short)f2bf(v.z); pk.w = (short)f2bf(v.w);
                *(short4*)&tileS[r * ROW_SH + lane * 4] = pk;
                float s = v.x * v.x + v.y * v.y + v.z * v.z + v.w * v.w;
                #pragma unroll
                for (int o = 32; o; o >>= 1) s += __shfl_xor(s, o, 64);
                if (lane == 0) sqs[r] = s;
            }
            // Barrier closes the fbuf-reuse hazard (phase-1 DMA writes must not
            // overtake phase-0 ds_reads of the same slots) and is the final
            // cross-wave fence before MFMA on the last phase.
            __syncthreads();
        }
        // Rows m..T*16-1 never written: garbage bf16/sqs only reach masked-out
        // C entries (MFMA per-element independence) — proven safe.
        const int np = T * (T + 1) / 2;
        for (int idx = wave; idx < np; idx += 8) {
            int ta = 0, r = idx;
            while (r >= T - ta) { r -= T - ta; ++ta; }
            int tb = ta + r;
            accum += tile16(tileS, sqs, ta * 16, tb * 16, ta * 16, tb * 16, m, lane);
        }
    } else {
        // general fallback: 48-row panel pairs (correct for any m; ~never runs)
        const int P = (m + PANEL - 1) / PANEL;
        for (int pi = 0; pi < P; ++pi)
        for (int pj = pi; pj < P; ++pj) {
            __syncthreads();
            stage(pred, bkt_g, m, pi * PANEL, 0,     PANEL, tileS, sqs, wave, lane);
            stage(pred, bkt_g, m, pj * PANEL, PANEL, PANEL, tileS, sqs, wave, lane);
            __syncthreads();
            for (int idx = wave; idx < 9; idx += 8) {
                int ta = idx / 3, tb = idx % 3;
                accum += tile16(tileS, sqs, ta * 16, PANEL + tb * 16,
                                pi * PANEL + ta * 16, pj * PANEL + tb * 16, m, lane);
            }
        }
    }

    #pragma unroll
    for (int o = 32; o; o >>= 1) accum += __shfl_xor(accum, o, 64);
    if (lane == 0) wsum[wave] = accum;
    __syncthreads();
    if (t == 0) {
        double bs = 0.0;
        #pragma unroll
        for (int w = 0; w < 8; ++w) bs += (double)wsum[w];
        __hip_atomic_store(&psum[c], bs, __ATOMIC_RELAXED, __HIP_MEMORY_SCOPE_AGENT);
        __hip_atomic_store(&pcnt[c], (double)m * (double)(m - 1) * 0.5,
                           __ATOMIC_RELEASE, __HIP_MEMORY_SCOPE_AGENT);
    }

    if (c == 0) {
        // gather all 100 per-class partials (write-once flags, distinct lines —
        // proven-safe spin pattern from rounds 0/1)
        double mys = 0.0, myc = 0.0;
        if (t < N_CLS) {
            unsigned long long bits;
            do {
                bits = __hip_atomic_load((const unsigned long long*)&pcnt[t],
                                         __ATOMIC_ACQUIRE, __HIP_MEMORY_SCOPE_AGENT);
            } while (bits >> 63);             // poison is negative; pcnt >= 0.0
            myc = __longlong_as_double((long long)bits);
            unsigned long long sb = __hip_atomic_load((const unsigned long long*)&psum[t],
                                         __ATOMIC_RELAXED, __HIP_MEMORY_SCOPE_AGENT);
            mys = __longlong_as_double((long long)sb);
        }
        __syncthreads();                      // staging data dead; reuse tileS
        double* red_s = (double*)tileS;
        double* red_c = red_s + 128;
        if (t < 128) { red_s[t] = (t < N_CLS) ? mys : 0.0;
                       red_c[t] = (t < N_CLS) ? myc : 0.0; }
        __syncthreads();
        for (int w = 64; w; w >>= 1) {
            if (t < w) { red_s[t] += red_s[t + w]; red_c[t] += red_c[t + w]; }
            __syncthreads();
        }
        if (t == 0) out[0] = (float)(red_c[0] > 0.0 ? red_s[0] / red_c[0] : 0.0);
    }
}

extern "C" void kernel_launch(void* const* d_in, const int* in_sizes, int n_in,
                              void* d_out, int out_size, void* d_ws, size_t ws_size,
                              hipStream_t stream) {
    const float* pred  = (const float*)d_in[0];
    const int* targets = (const int*)d_in[1];
    float* out         = (float*)d_out;
    const int n = in_sizes[1];     // 8192

    char* ws = (char*)d_ws;
    size_t off = 0;
    double* psum     = (double*)(ws + off); off += N_CLS * 8;
    double* pcnt     = (double*)(ws + off); off += N_CLS * 8;
    int*    bucket_g = (int*)(ws + off);    // N_CLS * n ints = 3.2 MB, fits ws

    k_cls<<<N_CLS, 512, 0, stream>>>(pred, targets, n, bucket_g, psum, pcnt, out);
}